// Round 12
// baseline (1759.459 us; speedup 1.0000x reference)
//
#include <hip/hip_runtime.h>
#include <cstddef>

#define Bn 32
#define Sn 2048
#define Hn 256
#define Ln 2
#define CHUNK 32
#define NCHUNK (Sn / CHUNK)   // 64
#define PACE 2                // proj1 runs at most PACE+1 chunks ahead of rec1

#define PSTR 10
#define PBUF (Hn * PSTR)      // 2560 words per partial buffer

#define FPAD 32               // one flag per 128B line
#define NFL (5 * Bn)          // 2 xp1-half + 1 y1 + 2 xp2-half per batch

typedef float f32x2 __attribute__((ext_vector_type(2)));

// ---------------------------------------------------------------------------
// ZERO-FENCE pipeline (r10/r11-proven): producers make cross-block data
// L3-visible with relaxed agent-scope (sc1, write-through) stores; consumers
// read normal-cached except where their XCD L2 can provably hold a stale
// copy (rec2's xp: in-place aliases of co-XCD rec1's cached xp1 lines; both
// recs' 2 boundary rows: their own pre-flag cross-chunk prefetch targets).
// No __threadfence in the binary -> no bulk L2 invalidations.
// Flag slots (chunk-granular monotone counters):
//   (0..1,b): xp1[b] half j ready   (proj1 half-blocks)
//   (2,   b): y1[b] done            (rec1)  -- also paces proj1
//   (3..4,b): xp2[b] half j ready   (proj2 half-blocks)
// ---------------------------------------------------------------------------
__device__ unsigned g_flags[NFL * FPAD];

__global__ void zero_flags_k() {
  int i = threadIdx.x;
  if (i < NFL)
    __hip_atomic_store(&g_flags[i * FPAD], 0u, __ATOMIC_RELAXED,
                       __HIP_MEMORY_SCOPE_AGENT);
}

__device__ __forceinline__ float tanh_fast(float x) {
  // tanh(x) = 1 - 2/(exp(2x)+1); saturates correctly at +/-inf
  float e = __expf(2.0f * x);
  return 1.0f - 2.0f / (e + 1.0f);
}

// sc1 (agent-scope) relaxed data ops: read/write the L3 coherence point.
__device__ __forceinline__ float ldg_dev(const float* p) {
  return __hip_atomic_load(p, __ATOMIC_RELAXED, __HIP_MEMORY_SCOPE_AGENT);
}
__device__ __forceinline__ void stg_dev(float* p, float v) {
  __hip_atomic_store(p, v, __ATOMIC_RELAXED, __HIP_MEMORY_SCOPE_AGENT);
}

// pure poll over n flags (stride Bn*FPAD apart). NO fence. s_sleep(32)
// (~1us granularity): only truly-waiting blocks sleep; steady-state polls
// return on the first load.
__device__ __forceinline__ void poll_ge_n(unsigned* base, int n, unsigned tgt) {
  for (int q = 0; q < n; ++q) {
    unsigned* f = base + (size_t)q * Bn * FPAD;
    while (__hip_atomic_load(f, __ATOMIC_RELAXED, __HIP_MEMORY_SCOPE_AGENT) < tgt)
      __builtin_amdgcn_s_sleep(32);
  }
}

// publisher: every wave drains its (sc1 write-through) stores, barrier,
// then t0 stores the flag. NO fence.
__device__ __forceinline__ void publish(unsigned* f, unsigned val, int t) {
  asm volatile("s_waitcnt vmcnt(0)" ::: "memory");
  __syncthreads();
  if (t == 0)
    __hip_atomic_store(f, val, __ATOMIC_RELAXED, __HIP_MEMORY_SCOPE_AGENT);
}

// ---------------------------------------------------------------------------
// Recurrence body — unchanged r11 step structure (pk_fma FMA, stride-10
// swizzled slot-major partials, no-shfl 8-slot reduce, hbuf h-exchange,
// single raw s_barrier/step, depth-2 xp prefetch, zero-fence wrappers).
// ---------------------------------------------------------------------------
template <bool XP_SC1, bool Y_SC1>
__device__ void rec_body(const float* __restrict__ xp_b,
                         const float* __restrict__ Whh,
                         const float* __restrict__ bhh,
                         const float* __restrict__ h0_b,
                         float* __restrict__ y_b,
                         float* __restrict__ hfin_b,
                         unsigned* wbase, int nw, unsigned* pub,
                         float* part, float* hbuf) {
  const int t = threadIdx.x;
  const int lane = t & 63;
  const int w = t >> 6;                   // 0..7
  const int ocol = 32 * w + (lane & 31);  // output this lane reduces

  // Wreg[r][c2] = (Whh[lane+64r][32w+2c2], Whh[lane+64r][32w+2c2+1])
  f32x2 Wreg[4][16];
#pragma unroll
  for (int r = 0; r < 4; ++r)
#pragma unroll
    for (int q = 0; q < 8; ++q) {
      float4 v = *(const float4*)&Whh[(size_t)(lane + 64 * r) * Hn + 32 * w + 4 * q];
      Wreg[r][2 * q + 0] = f32x2{v.x, v.y};
      Wreg[r][2 * q + 1] = f32x2{v.z, v.w};
    }
#pragma unroll
  for (int r = 0; r < 4; ++r)
#pragma unroll
    for (int c = 0; c < 16; ++c)
      asm("" : "+v"(Wreg[r][c]));

  // partial write base: row = lane(+64r), slot = w ^ ((lane>>3)&3)
  const int pw0 = PSTR * lane + (w ^ ((lane >> 3) & 3));
  const float bias = bhh[ocol];

  f32x2 hv[16];
#pragma unroll
  for (int j = 0; j < 8; ++j) {
    float4 v = *(const float4*)&h0_b[32 * w + 4 * j];
    hv[2 * j + 0] = f32x2{v.x, v.y};
    hv[2 * j + 1] = f32x2{v.z, v.w};
  }

  for (int c = 0; c < NCHUNK; ++c) {
    // acquire this chunk's xp halves: pure poll, no fence
    if (t == 0) poll_ge_n(wbase, nw, c + 1);
    __syncthreads();

    const int s0 = c * CHUNK;
    // sc1 reload of the two rows our pre-flag cross-chunk prefetch touched
    float xp_cur = ldg_dev(&xp_b[(size_t)s0 * Hn + ocol]);
    float xp_n1  = ldg_dev(&xp_b[(size_t)(s0 + 1) * Hn + ocol]);

    for (int ss = 0; ss < CHUNK; ++ss) {
      const int s = s0 + ss;
      // depth-2 prefetch: consumed two steps later (~1.6us of cover)
      float xp_n2 = 0.0f;
      if (s + 2 < Sn)
        xp_n2 = XP_SC1 ? ldg_dev(&xp_b[(size_t)(s + 2) * Hn + ocol])
                       : xp_b[(size_t)(s + 2) * Hn + ocol];

      // ---- FMA phase: 64 v_pk_fma_f32 per lane
      f32x2 acc0 = {0.f, 0.f}, acc1 = {0.f, 0.f};
      f32x2 acc2 = {0.f, 0.f}, acc3 = {0.f, 0.f};
#pragma unroll
      for (int cc = 0; cc < 16; ++cc) {
        asm("v_pk_fma_f32 %0, %1, %2, %0" : "+v"(acc0) : "v"(Wreg[0][cc]), "v"(hv[cc]));
        asm("v_pk_fma_f32 %0, %1, %2, %0" : "+v"(acc1) : "v"(Wreg[1][cc]), "v"(hv[cc]));
        asm("v_pk_fma_f32 %0, %1, %2, %0" : "+v"(acc2) : "v"(Wreg[2][cc]), "v"(hv[cc]));
        asm("v_pk_fma_f32 %0, %1, %2, %0" : "+v"(acc3) : "v"(Wreg[3][cc]), "v"(hv[cc]));
      }
      float* pbuf = &part[(s & 1) * PBUF];
      pbuf[pw0       ] = acc0.x + acc0.y;
      pbuf[pw0 +  640] = acc1.x + acc1.y;
      pbuf[pw0 + 1280] = acc2.x + acc2.y;
      pbuf[pw0 + 1920] = acc3.x + acc3.y;

      asm volatile("s_waitcnt lgkmcnt(0)" ::: "memory");
      __builtin_amdgcn_s_barrier();
      __builtin_amdgcn_sched_barrier(0);

      // ---- reduce: every lane sums all 8 slots of its output (no shfl)
      const f32x2* prow = (const f32x2*)&pbuf[PSTR * ocol];
      f32x2 p0 = prow[0], p1 = prow[1], p2 = prow[2], p3 = prow[3];
      f32x2 q01 = p0 + p1;          // v_pk_add_f32
      f32x2 q23 = p2 + p3;
      f32x2 qq = q01 + q23;
      float hn = tanh_fast((qq.x + qq.y) + xp_cur + bias);
      if (lane < 32) {
        hbuf[ocol] = hn;
        if (Y_SC1) stg_dev(&y_b[(size_t)s * Hn + ocol], hn);  // L3 write-through
        else       y_b[(size_t)s * Hn + ocol] = hn;           // final output
      }
      xp_cur = xp_n1;
      xp_n1 = xp_n2;

      // ---- wave-local hv reload (only this wave's own 32 outputs)
      __builtin_amdgcn_wave_barrier();   // keep reads after the masked write
#pragma unroll
      for (int j = 0; j < 8; ++j) {
        float4 v = *(const float4*)&hbuf[32 * w + 4 * j];
        hv[2 * j + 0] = f32x2{v.x, v.y};
        hv[2 * j + 1] = f32x2{v.z, v.w};
      }
    }

    if (pub) publish(pub, (unsigned)(c + 1), t);
  }

  if (lane < 32) hfin_b[ocol] = hbuf[ocol];
}

// ---------------------------------------------------------------------------
// Projection worker, CHUNK=32 rows: one block per (layer, batch, N-half).
//   C[32, 2x64] = A[32,256] * W[.,256]^T + bias, k ascending (absmax-stable:
//   per-output k summation order identical to all prior rounds).
// A,W normal cached; C (xp) sc1 write-through (consumed cross-XCD by rec).
// pace: proj1 throttles against rec1's y1 flag (lookahead PACE+1) so its
// GEMM power spreads over the whole span instead of a 64-CU sprint ->
// less clock droop on the rec CUs. ~5us work / ~26us cadence.
// ---------------------------------------------------------------------------
__device__ void proj_body(const float* __restrict__ Ab,
                          const float* __restrict__ W,
                          const float* __restrict__ bias,
                          float* __restrict__ Cb,
                          unsigned* waitf, unsigned* pace, unsigned* pub,
                          int nt0, int nt1,
                          float* smem) {
  const int t = threadIdx.x;
  const int tx = t & 15;    // 4 cols each
  const int ty = t >> 4;    // 0..31, 1 row each
  float (*As)[34] = (float(*)[34])smem;              // [64 k][32 m]
  float (*Bs)[68] = (float(*)[68])(smem + 64 * 34);  // [64 k][64 n]

  for (int c = 0; c < NCHUNK; ++c) {
    if (waitf || pace) {
      if (t == 0) {
        if (waitf) poll_ge_n(waitf, 1, c + 1);
        if (pace && c > PACE) poll_ge_n(pace, 1, (unsigned)(c - PACE));
      }
      __syncthreads();
    }
    const float* A = Ab + (size_t)(c * CHUNK) * Hn;
    float* C = Cb + (size_t)(c * CHUNK) * Hn;

    for (int nt = nt0; nt < nt1; ++nt) {
      const int n0 = nt * 64;
      float acc[4] = {0.f, 0.f, 0.f, 0.f};
      for (int kc = 0; kc < Hn; kc += 64) {
        {
          int mm = t >> 4;               // 0..31
          int kk = (t & 15) << 2;
          float4 av = *(const float4*)&A[(size_t)mm * Hn + kc + kk];
          As[kk + 0][mm] = av.x; As[kk + 1][mm] = av.y;
          As[kk + 2][mm] = av.z; As[kk + 3][mm] = av.w;
        }
#pragma unroll
        for (int r = 0; r < 2; ++r) {
          int idx = t + 512 * r;         // 0..1023 -> 64 W-rows x 16 float4
          int mm = idx >> 4;
          int kk = (idx & 15) << 2;
          float4 wv = *(const float4*)&W[(size_t)(n0 + mm) * Hn + kc + kk];
          Bs[kk + 0][mm] = wv.x; Bs[kk + 1][mm] = wv.y;
          Bs[kk + 2][mm] = wv.z; Bs[kk + 3][mm] = wv.w;
        }
        __syncthreads();
#pragma unroll
        for (int k = 0; k < 64; ++k) {
          float a = As[k][ty];
          float4 bv = *(const float4*)&Bs[k][tx << 2];
          acc[0] += a * bv.x; acc[1] += a * bv.y;
          acc[2] += a * bv.z; acc[3] += a * bv.w;
        }
        __syncthreads();
      }
      float4 bb = *(const float4*)&bias[n0 + (tx << 2)];
      float* cp = &C[(size_t)ty * Hn + n0 + (tx << 2)];
      stg_dev(cp + 0, acc[0] + bb.x);
      stg_dev(cp + 1, acc[1] + bb.y);
      stg_dev(cp + 2, acc[2] + bb.z);
      stg_dev(cp + 3, acc[3] + bb.w);
    }

    publish(pub, (unsigned)(c + 1), t);
  }
}

// ---------------------------------------------------------------------------
// Fused pipeline kernel. 192 blocks x 512 threads:
//   [  0, 32): rec1, batch b      polls xp1[b] (2 flags), publishes y1[b]
//   [ 32, 64): rec2, batch b      polls xp2[b] (2 flags)
//   [ 64,128): proj1 (b, half j)  paced by y1[b]; publishes xp1[b] half j
//   [128,192): proj2 (b, half j)  polls y1[b]; publishes xp2[b] half j
// In-place xp reuse is flag-ordered: proj1[c] -> rec1[c] -> (y1 flag) ->
// proj2[c] -> rec2[c]; rec1's 2-row lookahead into c+1 is disjoint and
// sc1-reloaded post-flag. proj1 pacing cannot deadlock: chunks 0..PACE are
// produced unconditionally and rec1 chunk c needs only xp1 chunks <= c.
// ---------------------------------------------------------------------------
__global__ __launch_bounds__(512)
__attribute__((amdgpu_waves_per_eu(2, 2)))
void fused(
    const float* __restrict__ x, const float* __restrict__ h0,
    const float* __restrict__ Wih, const float* __restrict__ Whh,
    const float* __restrict__ bih, const float* __restrict__ bhh,
    float* __restrict__ yout, float* __restrict__ fin,
    float* __restrict__ xpws) {
  __shared__ float smem[2 * 64 * 68];   // 34.8 KB; rec carves part+hbuf
  const int bid = blockIdx.x;

  if (bid < 32) {
    const int b = bid;
    rec_body<false, true>(xpws + (size_t)b * Sn * Hn, Whh, bhh,
                          h0 + (size_t)b * Hn,
                          yout + (size_t)b * Sn * Hn, fin + (size_t)b * Hn,
                          &g_flags[(0 * Bn + b) * FPAD], 2,
                          &g_flags[(2 * Bn + b) * FPAD],
                          smem, smem + 2 * PBUF);
  } else if (bid < 64) {
    const int b = bid - 32;
    rec_body<true, false>(xpws + (size_t)b * Sn * Hn, Whh + Hn * Hn, bhh + Hn,
                          h0 + (size_t)Bn * Hn + (size_t)b * Hn,
                          yout + (size_t)b * Sn * Hn,
                          fin + (size_t)Bn * Hn + (size_t)b * Hn,
                          &g_flags[(3 * Bn + b) * FPAD], 2, nullptr,
                          smem, smem + 2 * PBUF);
  } else if (bid < 128) {
    const int q = bid - 64;
    const int b = q & 31, j = q >> 5;    // half j: tiles 2j..2j+1
    proj_body(x + (size_t)b * Sn * Hn, Wih, bih, xpws + (size_t)b * Sn * Hn,
              nullptr, &g_flags[(2 * Bn + b) * FPAD],
              &g_flags[((0 + j) * Bn + b) * FPAD],
              2 * j, 2 * j + 2, smem);
  } else {
    const int q = bid - 128;
    const int b = q & 31, j = q >> 5;    // half j: tiles 2j..2j+1
    proj_body(yout + (size_t)b * Sn * Hn, Wih + Hn * Hn, bih + Hn,
              xpws + (size_t)b * Sn * Hn,
              &g_flags[(2 * Bn + b) * FPAD], nullptr,
              &g_flags[((3 + j) * Bn + b) * FPAD],
              2 * j, 2 * j + 2, smem);
  }
}

// ---------------------------------------------------------------------------
// Launch: zero flags, then the single fully-pipelined kernel.
// ws needs Bn*Sn*Hn*4 = 64 MiB (xp buffer, shared by both layers in-place).
// ---------------------------------------------------------------------------
extern "C" void kernel_launch(void* const* d_in, const int* in_sizes, int n_in,
                              void* d_out, int out_size, void* d_ws, size_t ws_size,
                              hipStream_t stream) {
  const float* x   = (const float*)d_in[0];
  const float* h0  = (const float*)d_in[1];
  const float* Wih = (const float*)d_in[2];
  const float* Whh = (const float*)d_in[3];
  const float* bih = (const float*)d_in[4];
  const float* bhh = (const float*)d_in[5];

  float* out = (float*)d_out;
  float* yout = out;                              // [Bn,Sn,Hn]
  float* fin  = out + (size_t)Bn * Sn * Hn;       // [Ln,Bn,Hn]
  float* xpws = (float*)d_ws;                     // [Bn,Sn,Hn] scratch

  zero_flags_k<<<1, 256, 0, stream>>>();
  fused<<<192, 512, 0, stream>>>(x, h0, Wih, Whh, bih, bhh, yout, fin, xpws);
}